// Round 3
// baseline (453.969 us; speedup 1.0000x reference)
//
#include <hip/hip_runtime.h>

typedef unsigned short u16;
typedef __bf16 bf16x8 __attribute__((ext_vector_type(8)));
typedef float f32x4 __attribute__((ext_vector_type(4)));

typedef __attribute__((address_space(1))) const void* as1_cvp;
typedef __attribute__((address_space(3))) void* as3_vp;

// ---------- bf16 helpers ----------
__device__ __forceinline__ float b2f(u16 u) {
  union { unsigned int i; float f; } x; x.i = ((unsigned int)u) << 16; return x.f;
}
__device__ __forceinline__ u16 f2b(float f) {
  union { float f; unsigned int i; } x; x.f = f;
  unsigned int u = x.i;
  u += 0x7fffu + ((u >> 16) & 1u);   // round-to-nearest-even
  return (u16)(u >> 16);
}

// ---------- dtype detector: flag=1 if inputs are fp32, 0 if bf16 ----------
__global__ void k_detect(const u16* __restrict__ x, int* __restrict__ flag) {
  int t = threadIdx.x;
  int sane = 0;
#pragma unroll
  for (int i = 0; i < 8; ++i) {
    u16 u = x[t * 8 + i];
    int e = (u >> 7) & 0xFF;
    sane += (u == 0 || (e >= 100 && e <= 150)) ? 1 : 0;
  }
#pragma unroll
  for (int off = 32; off >= 1; off >>= 1) sane += __shfl_xor(sane, off);
  if (t == 0) *flag = (sane < 480) ? 1 : 0;
}

// ---------- x -> bf16 downconvert; no-op when inputs already bf16 ----------
__global__ void k_convert(const void* __restrict__ xin, u16* __restrict__ xb,
                          const int* __restrict__ flagp) {
  if (!*flagp) return;  // bf16 inputs: GEMM1 reads raw input directly
  long i = ((long)blockIdx.x * 256 + threadIdx.x) * 4;
  float4 v = *(const float4*)((const float*)xin + i);
  u16* o = xb + i;
  o[0] = f2b(v.x); o[1] = f2b(v.y); o[2] = f2b(v.z); o[3] = f2b(v.w);
}

// ---------- W[K][N] -> WT[N][K] as bf16 ----------
__global__ void k_transpose(const void* __restrict__ W, u16* __restrict__ WT,
                            const int* __restrict__ flagp, int K, int N) {
  __shared__ u16 tile[32][33];
  int f = *flagp;
  int n0 = blockIdx.x * 32, k0 = blockIdx.y * 32;
  int tx = threadIdx.x, ty = threadIdx.y;
#pragma unroll
  for (int i = 0; i < 32; i += 8) {
    long idx = (long)(k0 + ty + i) * N + n0 + tx;
    tile[ty + i][tx] = f ? f2b(((const float*)W)[idx]) : ((const u16*)W)[idx];
  }
  __syncthreads();
#pragma unroll
  for (int i = 0; i < 32; i += 8)
    WT[(long)(n0 + ty + i) * K + k0 + tx] = tile[tx][ty + i];
}

// ---------- bias in MFMA C-fragment order, bf16, mask baked in ----------
__global__ void k_biasfrag(const int* __restrict__ rel, const void* __restrict__ table,
                           u16* __restrict__ biasFrag, const int* __restrict__ flagp) {
  int t = blockIdx.x * 256 + threadIdx.x;   // 57344 total
  int f = *flagp;
  int ln = t & 63, r2 = t >> 6;
  int tj = r2 & 7, r3 = r2 >> 3;
  int ti = r3 % 7, h = r3 / 7;
  int col = ln & 15, qrow = ln >> 4;
  int j = tj * 16 + col;
  u16 v[4];
#pragma unroll
  for (int r = 0; r < 4; ++r) {
    int i = ti * 16 + qrow * 4 + r; if (i > 97) i = 97;
    float val;
    if (j < 98) {
      int rr = rel[i * 98 + j];
      val = f ? ((const float*)table)[rr * 16 + h] : b2f(((const u16*)table)[rr * 16 + h]);
    } else {
      val = -1e30f;
    }
    v[r] = f2b(val);
  }
  ushort4 out; out.x = v[0]; out.y = v[1]; out.z = v[2]; out.w = v[3];
  *(ushort4*)(biasFrag + (long)t * 4) = out;
}

// ========== 128x128 bf16 GEMM, 4 waves, BK=64, 64KiB LDS -> 2 blocks/CU =====
// C[M][N] = A[M][K] * BT[N][K]^T + bias.  Wave tile 64x64 (2m x 2n).
// TLP strategy: two independent blocks per CU overlap each other's staging /
// barrier / epilogue stalls (R1/R2 showed intra-block scheduling cannot).
// LDS per matrix: [buf(2)][row(128)][chunk16B(8)], T2 XOR swizzle
// chunk ^= (row&7): linear global_load_lds dest + inverse-swizzled per-lane
// GLOBAL source + swizzled ds_read addresses (rule 21; 2-way residual
// conflict only, which is free).
// K-tile loop (2 barriers): read 16 frags, 32 MFMA; lgkm0+BAR1 (buf free);
// stage kt+2 into buf; vmcnt(8) = kt+1 complete (issued one full K-tile ago);
// BAR2 publishes kt+1.  Requires M%128==0, N%128==0, K%64==0, grid%8==0.
#define STAGE4(arr, bufi, src, kt) do {                                        \
    u16* _d = &arr[(bufi) * 8192 + w * 512];                                   \
    const u16* _s = (src) + (long)(kt) * 64;                                   \
    __builtin_amdgcn_global_load_lds((as1_cvp)(const void*)(_s),           (as3_vp)(_d),        16, 0, 0); \
    __builtin_amdgcn_global_load_lds((as1_cvp)(const void*)(_s + 32L * K), (as3_vp)(_d + 2048), 16, 0, 0); \
    __builtin_amdgcn_global_load_lds((as1_cvp)(const void*)(_s + 64L * K), (as3_vp)(_d + 4096), 16, 0, 0); \
    __builtin_amdgcn_global_load_lds((as1_cvp)(const void*)(_s + 96L * K), (as3_vp)(_d + 6144), 16, 0, 0); \
  } while (0)

__global__ __launch_bounds__(256, 2) void k_gemm128(
    const u16* __restrict__ A_raw, const u16* __restrict__ A_conv,
    const u16* __restrict__ BT, const void* __restrict__ bias, void* __restrict__ C,
    const int* __restrict__ flagp, int N, int K, int out_follows_flag, int NBY) {
  __shared__ __align__(16) u16 As[16384];   // 32 KiB: 2 x 128 x 64 bf16
  __shared__ __align__(16) u16 Bs[16384];   // 32 KiB
  const int f = *flagp;
  const u16* A = f ? A_conv : A_raw;
  const int t = threadIdx.x, w = t >> 6, ln = t & 63;
  // T1: XCD-aware chunked swizzle (grid%8==0); consecutive wg in an XCD share
  // the same A row-panel (col-tile fast) -> A reused NBY times from XCD L2
  const int nwg = gridDim.x, cpx = nwg >> 3;
  const int wg = (blockIdx.x & 7) * cpx + (blockIdx.x >> 3);
  const long bm = (long)(wg / NBY) * 128, bn = (long)(wg % NBY) * 128;
  const int NK = K >> 6;
  const int wm = w >> 1, wn = w & 1;
  const int col = ln & 15, qrow = ln >> 4, c7 = ln & 7;
  // staging role: rows w*8+(ln>>3) (+32 per extra instr), chunk inverse-swizzled
  const int srow = w * 8 + (ln >> 3);
  const int schunk = (ln & 7) ^ ((ln >> 3) & 7);
  const u16* aS = A + (bm + srow) * (long)K + schunk * 8;
  const u16* bS = BT + (bn + srow) * (long)K + schunk * 8;
  // swizzled ds_read bases / k-chunk offsets (u16 units)
  const u16* aRd = &As[(wm * 64 + col) * 64];
  const u16* bRd = &Bs[(wn * 64 + col) * 64];
  const int kc7 = col & 7;
  const int ko0 = (qrow ^ kc7) * 8;        // kk=0 chunk
  const int ko1 = ((4 + qrow) ^ kc7) * 8;  // kk=1 chunk
  (void)c7;
  // bias loads pinned BEFORE prologue stages: they are the oldest vmem ops, so
  // the first vmcnt(8) retires them together with kt0
  float bv[4];
#pragma unroll
  for (int ni = 0; ni < 4; ++ni) {
    long c = bn + wn * 64 + ni * 16 + col;
    bv[ni] = f ? ((const float*)bias)[c] : b2f(((const u16*)bias)[c]);
  }
  asm volatile("" ::: "memory");
  // prologue: stage kt0 and kt1 (16 loads/wave)
  STAGE4(As, 0, aS, 0); STAGE4(Bs, 0, bS, 0);
  STAGE4(As, 1, aS, 1); STAGE4(Bs, 1, bS, 1);
  asm volatile("s_waitcnt vmcnt(8)" ::: "memory");   // kt0 done, kt1 in flight
  __builtin_amdgcn_s_barrier();

  f32x4 acc[4][4] = {};
  for (int kt = 0; kt < NK; ++kt) {
    const int buf = kt & 1;
    const u16* aP = aRd + buf * 8192;
    const u16* bP = bRd + buf * 8192;
    bf16x8 a0[4], b0[4], a1[4], b1[4];
#pragma unroll
    for (int i = 0; i < 4; ++i) {
      a0[i] = *(const bf16x8*)(aP + i * 1024 + ko0);
      b0[i] = *(const bf16x8*)(bP + i * 1024 + ko0);
      a1[i] = *(const bf16x8*)(aP + i * 1024 + ko1);
      b1[i] = *(const bf16x8*)(bP + i * 1024 + ko1);
    }
    __builtin_amdgcn_s_setprio(1);
#pragma unroll
    for (int mi = 0; mi < 4; ++mi)
#pragma unroll
      for (int ni = 0; ni < 4; ++ni)
        acc[mi][ni] = __builtin_amdgcn_mfma_f32_16x16x32_bf16(a0[mi], b0[ni], acc[mi][ni], 0, 0, 0);
#pragma unroll
    for (int mi = 0; mi < 4; ++mi)
#pragma unroll
      for (int ni = 0; ni < 4; ++ni)
        acc[mi][ni] = __builtin_amdgcn_mfma_f32_16x16x32_bf16(a1[mi], b1[ni], acc[mi][ni], 0, 0, 0);
    __builtin_amdgcn_s_setprio(0);
    asm volatile("s_waitcnt lgkmcnt(0)" ::: "memory");  // all reads of buf done
    __builtin_amdgcn_s_barrier();                       // BAR1: buf free
    if (kt + 2 < NK) {
      STAGE4(As, buf, aS, kt + 2); STAGE4(Bs, buf, bS, kt + 2);
      asm volatile("s_waitcnt vmcnt(8)" ::: "memory");  // kt+1 fully staged
    } else if (kt + 1 < NK) {
      asm volatile("s_waitcnt vmcnt(0)" ::: "memory");
    }
    __builtin_amdgcn_s_barrier();                       // BAR2: publish kt+1
  }
  // ---- epilogue ----
  const int of = out_follows_flag ? f : 0;
#pragma unroll
  for (int mi = 0; mi < 4; ++mi)
#pragma unroll
    for (int ni = 0; ni < 4; ++ni)
#pragma unroll
      for (int r = 0; r < 4; ++r) {
        long row = bm + wm * 64 + mi * 16 + qrow * 4 + r;
        long c = bn + wn * 64 + ni * 16 + col;
        float v = acc[mi][ni][r] + bv[ni];
        if (of) ((float*)C)[row * N + c] = v;
        else    ((u16*)C)[row * N + c] = f2b(v);
      }
}

// ---------- fused window attention v2: one block per (b,h), 4 waves ----------
__global__ __launch_bounds__(256) void k_attn(
    const u16* __restrict__ qkv, const u16* __restrict__ biasFrag,
    u16* __restrict__ attnout) {
  __shared__ __align__(16) u16 Qs[112 * 32];     // aliased as Os after compute
  __shared__ __align__(16) u16 Ks[128 * 32];
  __shared__ __align__(16) u16 Vt[32 * 136];
  __shared__ __align__(16) u16 Ps[4][16 * 136];  // per-wave slot
  const int b = blockIdx.x, h = blockIdx.y;
  const int t = threadIdx.x, w = t >> 6, ln = t & 63;
  const u16* qbase = qkv + (long)b * 98 * 1536 + h * 32;
  {
    const int gr = ln >> 2, gc = (ln & 3) * 8;
    for (int n = w; n < 7; n += 4) {
      int g = n * 16 + gr; if (g > 97) g = 97;
      __builtin_amdgcn_global_load_lds((as1_cvp)(const void*)(qbase + (long)g * 1536 + gc),
                                       (as3_vp)(Qs + n * 512), 16, 0, 0);
    }
    for (int n = w; n < 8; n += 4) {
      int g = n * 16 + gr; if (g > 97) g = 97;
      __builtin_amdgcn_global_load_lds((as1_cvp)(const void*)(qbase + 512 + (long)g * 1536 + gc),
                                       (as3_vp)(Ks + n * 512), 16, 0, 0);
    }
  }
  for (int z = t; z < 32 * 19; z += 256) {
    int d = z / 19, q = z % 19;
    *(unsigned int*)&Vt[d * 136 + 98 + q * 2] = 0u;
  }
  for (int idx = t; idx < 784; idx += 256) {
    int i = idx >> 3, c4 = (idx & 7) * 4;
    ushort4 v4 = *(const ushort4*)(qbase + 1024 + (long)i * 1536 + c4);
    Vt[(c4 + 0) * 136 + i] = v4.x;
    Vt[(c4 + 1) * 136 + i] = v4.y;
    Vt[(c4 + 2) * 136 + i] = v4.z;
    Vt[(c4 + 3) * 136 + i] = v4.w;
  }
  __syncthreads();
  const int col = ln & 15, qrow = ln >> 4;
  const float scale = 0.17677669529663687f;  // 32^-0.5
  u16* Psw = &Ps[w][0];
  f32x4 o[2][2] = {{{0.f,0.f,0.f,0.f},{0.f,0.f,0.f,0.f}},{{0.f,0.f,0.f,0.f},{0.f,0.f,0.f,0.f}}};
  for (int tt = 0; tt < 2; ++tt) {
    const int ti = w + tt * 4;
    if (ti >= 7) break;
    const u16* bp = biasFrag + ((long)((h * 7 + ti) * 8) * 64 + ln) * 4;
    ushort4 bfv[8];
#pragma unroll
    for (int tj = 0; tj < 8; ++tj) bfv[tj] = *(const ushort4*)(bp + tj * 256);
    bf16x8 aq = *(const bf16x8*)&Qs[(ti * 16 + col) * 32 + qrow * 8];
    f32x4 s[8];
#pragma unroll
    for (int tj = 0; tj < 8; ++tj) {
      bf16x8 bk = *(const bf16x8*)&Ks[(tj * 16 + col) * 32 + qrow * 8];
      f32x4 z = {0.f, 0.f, 0.f, 0.f};
      s[tj] = __builtin_amdgcn_mfma_f32_16x16x32_bf16(aq, bk, z, 0, 0, 0);
    }
#pragma unroll
    for (int r = 0; r < 4; ++r) {
      float vals[8]; float m = -1e30f;
#pragma unroll
      for (int tj = 0; tj < 8; ++tj) {
        u16 bb = (r == 0) ? bfv[tj].x : (r == 1) ? bfv[tj].y : (r == 2) ? bfv[tj].z : bfv[tj].w;
        float v = fmaf(s[tj][r], scale, b2f(bb));
        vals[tj] = v; m = fmaxf(m, v);
      }
#pragma unroll
      for (int off = 1; off < 16; off <<= 1) m = fmaxf(m, __shfl_xor(m, off));
      float sum = 0.f;
#pragma unroll
      for (int tj = 0; tj < 8; ++tj) { vals[tj] = __expf(vals[tj] - m); sum += vals[tj]; }
#pragma unroll
      for (int off = 1; off < 16; off <<= 1) sum += __shfl_xor(sum, off);
      float inv = 1.f / sum;
      const int rt = qrow * 4 + r;
#pragma unroll
      for (int tj = 0; tj < 8; ++tj)
        Psw[rt * 136 + tj * 16 + col] = f2b(vals[tj] * inv);
    }
#pragma unroll
    for (int ks = 0; ks < 4; ++ks) {
      bf16x8 ap  = *(const bf16x8*)&Psw[col * 136 + ks * 32 + qrow * 8];
      bf16x8 bv0 = *(const bf16x8*)&Vt[col * 136 + ks * 32 + qrow * 8];
      bf16x8 bv1 = *(const bf16x8*)&Vt[(16 + col) * 136 + ks * 32 + qrow * 8];
      o[tt][0] = __builtin_amdgcn_mfma_f32_16x16x32_bf16(ap, bv0, o[tt][0], 0, 0, 0);
      o[tt][1] = __builtin_amdgcn_mfma_f32_16x16x32_bf16(ap, bv1, o[tt][1], 0, 0, 0);
    }
  }
  __syncthreads();
  u16* Os = Qs;
#pragma unroll
  for (int tt = 0; tt < 2; ++tt) {
    const int ti = w + tt * 4;
    if (ti >= 7) continue;
#pragma unroll
    for (int r = 0; r < 4; ++r) {
      const int i = ti * 16 + qrow * 4 + r;
      if (i < 98) {
        Os[i * 32 + col]      = f2b(o[tt][0][r]);
        Os[i * 32 + 16 + col] = f2b(o[tt][1][r]);
      }
    }
  }
  __syncthreads();
  u16* obase = attnout + (long)b * 98 * 512 + h * 32;
  for (int idx = t; idx < 784; idx += 256) {
    int i = idx >> 3, c4 = (idx & 7) * 4;
    *(ushort4*)(obase + (long)i * 512 + c4) = *(const ushort4*)&Os[i * 32 + c4];
  }
}

extern "C" void kernel_launch(void* const* d_in, const int* in_sizes, int n_in,
                              void* d_out, int out_size, void* d_ws, size_t ws_size,
                              hipStream_t stream) {
  (void)in_sizes; (void)n_in; (void)out_size; (void)ws_size;
  char* p = (char*)d_ws;
  u16* qkvbuf   = (u16*)p;  p += 50176L * 1536 * 2;   // 154,140,672
  u16* attnbuf  = (u16*)p;  u16* xb = attnbuf; p += 50176L * 512 * 2;  // 51,380,224
  u16* wqkvT    = (u16*)p;  p += 1536L * 512 * 2;     // 1,572,864
  u16* wprojT   = (u16*)p;  p += 512L * 512 * 2;      // 524,288
  u16* biasFrag = (u16*)p;  p += 57344L * 4 * 2;      // 458,752
  int* flagp    = (int*)p;

  k_detect<<<1, 64, 0, stream>>>((const u16*)d_in[0], flagp);
  k_convert<<<25088, 256, 0, stream>>>(d_in[0], xb, flagp);
  k_transpose<<<dim3(48, 16), dim3(32, 8), 0, stream>>>(d_in[1], wqkvT, flagp, 512, 1536);
  k_transpose<<<dim3(16, 16), dim3(32, 8), 0, stream>>>(d_in[3], wprojT, flagp, 512, 512);
  k_biasfrag<<<224, 256, 0, stream>>>((const int*)d_in[6], d_in[5], biasFrag, flagp);
  // qkv = x @ qkv_w + qkv_b   [50176 x 1536], 392x12 tiles of 128^2
  k_gemm128<<<dim3(392 * 12), 256, 0, stream>>>((const u16*)d_in[0], xb, wqkvT, d_in[2],
                                                qkvbuf, flagp, 1536, 512, 0, 12);
  // attention -> attnbuf [50176 x 512]
  k_attn<<<dim3(512, 16), 256, 0, stream>>>(qkvbuf, biasFrag, attnbuf);
  // out = attnbuf @ proj_w + proj_b   [50176 x 512], 392x4 tiles of 128^2
  k_gemm128<<<dim3(392 * 4), 256, 0, stream>>>(attnbuf, attnbuf, wprojT, d_in[4],
                                               d_out, flagp, 512, 512, 1, 4);
}

// Round 4
// 437.297 us; speedup vs baseline: 1.0381x; 1.0381x over previous
//
#include <hip/hip_runtime.h>

typedef unsigned short u16;
typedef __bf16 bf16x8 __attribute__((ext_vector_type(8)));
typedef float f32x4 __attribute__((ext_vector_type(4)));

typedef __attribute__((address_space(1))) const void* as1_cvp;
typedef __attribute__((address_space(3))) void* as3_vp;

// ---------- bf16 helpers ----------
__device__ __forceinline__ float b2f(u16 u) {
  union { unsigned int i; float f; } x; x.i = ((unsigned int)u) << 16; return x.f;
}
__device__ __forceinline__ u16 f2b(float f) {
  union { float f; unsigned int i; } x; x.f = f;
  unsigned int u = x.i;
  u += 0x7fffu + ((u >> 16) & 1u);   // round-to-nearest-even
  return (u16)(u >> 16);
}

// Packed-fragment layout (K=512, 16 k-chunks of 32):
//   element (r, k) lives at u16 index
//   ((r>>4)*16 + (k>>5))*512 + ((r&15) + (((k>>3)&3)<<4))*8 + (k&7)
// so an MFMA fragment (m-group g, k-chunk c) is 1KB contiguous at
// byte offset (g*16+c)*1024 + lane*16.  Both GEMM operands use this.

// ---------- dtype detector: flag=1 if inputs are fp32, 0 if bf16 ----------
__global__ void k_detect(const u16* __restrict__ x, int* __restrict__ flag) {
  int t = threadIdx.x;
  int sane = 0;
#pragma unroll
  for (int i = 0; i < 8; ++i) {
    u16 u = x[t * 8 + i];
    int e = (u >> 7) & 0xFF;
    sane += (u == 0 || (e >= 100 && e <= 150)) ? 1 : 0;
  }
#pragma unroll
  for (int off = 32; off >= 1; off >>= 1) sane += __shfl_xor(sane, off);
  if (t == 0) *flag = (sane < 480) ? 1 : 0;
}

// ---------- x -> packed bf16 fragments (always runs; 1 warp = 1 fragment) ----
__global__ void k_convert_pack(const void* __restrict__ xin, u16* __restrict__ xp,
                               const int* __restrict__ flagp) {
  const int f = *flagp;
  const int t = threadIdx.x, ln = t & 63;
  const int u = blockIdx.x * 4 + (t >> 6);          // fragment unit < 50176
  const long r = (long)(u >> 4) * 16 + (ln & 15);   // global row
  const int kbase = (u & 15) * 32 + (ln >> 4) * 8;  // k offset
  u16* dst = xp + ((long)u * 64 + ln) * 8;
  if (f) {
    const float* src = (const float*)xin + r * 512 + kbase;
    float4 v0 = *(const float4*)src;
    float4 v1 = *(const float4*)(src + 4);
    ushort4 s0, s1;
    s0.x = f2b(v0.x); s0.y = f2b(v0.y); s0.z = f2b(v0.z); s0.w = f2b(v0.w);
    s1.x = f2b(v1.x); s1.y = f2b(v1.y); s1.z = f2b(v1.z); s1.w = f2b(v1.w);
    *(ushort4*)dst = s0; *(ushort4*)(dst + 4) = s1;
  } else {
    const u16* src = (const u16*)xin + r * 512 + kbase;
    *(ushort4*)dst = *(const ushort4*)src;
    *(ushort4*)(dst + 4) = *(const ushort4*)(src + 4);
  }
}

// ---------- W[K=512][N] -> packed bf16 B-fragments (BT[n][k] frag order) ----
__global__ void k_pack_w(const void* __restrict__ W, u16* __restrict__ WP,
                         const int* __restrict__ flagp, int N) {
  const int f = *flagp;
  const int t = threadIdx.x, ln = t & 63;
  const int u = blockIdx.x * 4 + (t >> 6);          // fragment unit < N
  const int n = (u >> 4) * 16 + (ln & 15);
  const int k0 = (u & 15) * 32 + (ln >> 4) * 8;
  u16 v[8];
#pragma unroll
  for (int j = 0; j < 8; ++j) {
    long idx = (long)(k0 + j) * N + n;
    v[j] = f ? f2b(((const float*)W)[idx]) : ((const u16*)W)[idx];
  }
  u16* dst = WP + ((long)u * 64 + ln) * 8;
  ushort4 s0; s0.x = v[0]; s0.y = v[1]; s0.z = v[2]; s0.w = v[3];
  ushort4 s1; s1.x = v[4]; s1.y = v[5]; s1.z = v[6]; s1.w = v[7];
  *(ushort4*)dst = s0; *(ushort4*)(dst + 4) = s1;
}

// ---------- bias in MFMA C-fragment order, bf16, mask baked in ----------
__global__ void k_biasfrag(const int* __restrict__ rel, const void* __restrict__ table,
                           u16* __restrict__ biasFrag, const int* __restrict__ flagp) {
  int t = blockIdx.x * 256 + threadIdx.x;   // 57344 total
  int f = *flagp;
  int ln = t & 63, r2 = t >> 6;
  int tj = r2 & 7, r3 = r2 >> 3;
  int ti = r3 % 7, h = r3 / 7;
  int col = ln & 15, qrow = ln >> 4;
  int j = tj * 16 + col;
  u16 v[4];
#pragma unroll
  for (int r = 0; r < 4; ++r) {
    int i = ti * 16 + qrow * 4 + r; if (i > 97) i = 97;
    float val;
    if (j < 98) {
      int rr = rel[i * 98 + j];
      val = f ? ((const float*)table)[rr * 16 + h] : b2f(((const u16*)table)[rr * 16 + h]);
    } else {
      val = -1e30f;
    }
    v[r] = f2b(val);
  }
  ushort4 out; out.x = v[0]; out.y = v[1]; out.z = v[2]; out.w = v[3];
  *(ushort4*)(biasFrag + (long)t * 4) = out;
}

// ========== direct-fragment bf16 GEMM: no LDS, no barriers, pure dataflow ====
// C[M][N] = A*B^T + bias from PACKED fragment operands (layout above).
// 128x128 block tile, 4 waves of 64x64.  Every operand load is a coalesced
// 1KB global_load_dwordx4 (64 lanes x 16B); B panel is L2-resident, A panel
// reused across NBY column-blocks co-scheduled on one XCD (T1 swizzle).
// Explicit 2-deep prefetch pipeline with statically-named register sets
// (rule #20: no runtime-indexed frag arrays).  K fixed at 512 (16 chunks).
#define LOADSET(SA, SB, KC)                                                    \
  _Pragma("unroll") for (int mi = 0; mi < 4; ++mi) {                           \
    SA[mi][0] = *(const bf16x8*)(aB + mi * 16384 + (KC) * 1024);               \
    SA[mi][1] = *(const bf16x8*)(aB + mi * 16384 + (KC) * 1024 + 1024);        \
  }                                                                            \
  _Pragma("unroll") for (int ni = 0; ni < 4; ++ni) {                           \
    SB[ni][0] = *(const bf16x8*)(bB + ni * 16384 + (KC) * 1024);               \
    SB[ni][1] = *(const bf16x8*)(bB + ni * 16384 + (KC) * 1024 + 1024);        \
  }

#define MFMASET(SA, SB)                                                        \
  __builtin_amdgcn_s_setprio(1);                                               \
  _Pragma("unroll") for (int kk = 0; kk < 2; ++kk)                             \
  _Pragma("unroll") for (int mi = 0; mi < 4; ++mi)                             \
  _Pragma("unroll") for (int ni = 0; ni < 4; ++ni)                             \
      acc[mi][ni] = __builtin_amdgcn_mfma_f32_16x16x32_bf16(                   \
          SA[mi][kk], SB[ni][kk], acc[mi][ni], 0, 0, 0);                       \
  __builtin_amdgcn_s_setprio(0);

__global__ __launch_bounds__(256, 2) void k_gemm_direct(
    const u16* __restrict__ PA, const u16* __restrict__ PB,
    const void* __restrict__ bias, void* __restrict__ C,
    const int* __restrict__ flagp, int N, int out_follows_flag, int NBY) {
  const int f = *flagp;
  const int t = threadIdx.x, w = t >> 6, ln = t & 63;
  // T1: XCD-aware chunked swizzle (grid%8==0); bn-fast so same-bm blocks
  // share an XCD -> A panel served from that XCD's L2 after first touch
  const int nwg = gridDim.x, cpx = nwg >> 3;
  const int wg = (blockIdx.x & 7) * cpx + (blockIdx.x >> 3);
  const long bm = (long)(wg / NBY) * 128, bn = (long)(wg % NBY) * 128;
  const int wm = w >> 1, wn = w & 1;
  const int col = ln & 15, qrow = ln >> 4;
  // fragment base pointers (bytes): group stride 16KB, chunk stride 1KB
  const char* aB = (const char*)PA + ((bm >> 4) + wm * 4) * 16384L + ln * 16;
  const char* bB = (const char*)PB + ((bn >> 4) + wn * 4) * 16384L + ln * 16;
  float bv[4];
#pragma unroll
  for (int ni = 0; ni < 4; ++ni) {
    long c = bn + wn * 64 + ni * 16 + col;
    bv[ni] = f ? ((const float*)bias)[c] : b2f(((const u16*)bias)[c]);
  }
  f32x4 acc[4][4] = {};
  bf16x8 aX[4][2], bX[4][2], aY[4][2], bY[4][2];
  LOADSET(aX, bX, 0)
  LOADSET(aY, bY, 2)
#pragma unroll
  for (int kc = 0; kc < 16; kc += 4) {
    MFMASET(aX, bX)
    if (kc + 4 < 16) { LOADSET(aX, bX, kc + 4) }
    MFMASET(aY, bY)
    if (kc + 6 < 16) { LOADSET(aY, bY, kc + 6) }
  }
  // ---- epilogue: row-major C + bias ----
  const int of = out_follows_flag ? f : 0;
#pragma unroll
  for (int mi = 0; mi < 4; ++mi)
#pragma unroll
    for (int ni = 0; ni < 4; ++ni)
#pragma unroll
      for (int r = 0; r < 4; ++r) {
        long row = bm + wm * 64 + mi * 16 + qrow * 4 + r;
        long c = bn + wn * 64 + ni * 16 + col;
        float v = acc[mi][ni][r] + bv[ni];
        if (of) ((float*)C)[row * N + c] = v;
        else    ((u16*)C)[row * N + c] = f2b(v);
      }
}

// ---------- fused window attention: one block per (b,h), 4 waves ----------
// Output written PACKED (fragment order) so gemm2 reads it directly.
__global__ __launch_bounds__(256) void k_attn(
    const u16* __restrict__ qkv, const u16* __restrict__ biasFrag,
    u16* __restrict__ attnp) {
  __shared__ __align__(16) u16 Qs[112 * 32];     // aliased as Os after compute
  __shared__ __align__(16) u16 Ks[128 * 32];
  __shared__ __align__(16) u16 Vt[32 * 136];
  __shared__ __align__(16) u16 Ps[4][16 * 136];  // per-wave slot
  const int b = blockIdx.x, h = blockIdx.y;
  const int t = threadIdx.x, w = t >> 6, ln = t & 63;
  const u16* qbase = qkv + (long)b * 98 * 1536 + h * 32;
  {
    const int gr = ln >> 2, gc = (ln & 3) * 8;
    for (int n = w; n < 7; n += 4) {
      int g = n * 16 + gr; if (g > 97) g = 97;
      __builtin_amdgcn_global_load_lds((as1_cvp)(const void*)(qbase + (long)g * 1536 + gc),
                                       (as3_vp)(Qs + n * 512), 16, 0, 0);
    }
    for (int n = w; n < 8; n += 4) {
      int g = n * 16 + gr; if (g > 97) g = 97;
      __builtin_amdgcn_global_load_lds((as1_cvp)(const void*)(qbase + 512 + (long)g * 1536 + gc),
                                       (as3_vp)(Ks + n * 512), 16, 0, 0);
    }
  }
  for (int z = t; z < 32 * 19; z += 256) {
    int d = z / 19, q = z % 19;
    *(unsigned int*)&Vt[d * 136 + 98 + q * 2] = 0u;
  }
  for (int idx = t; idx < 784; idx += 256) {
    int i = idx >> 3, c4 = (idx & 7) * 4;
    ushort4 v4 = *(const ushort4*)(qbase + 1024 + (long)i * 1536 + c4);
    Vt[(c4 + 0) * 136 + i] = v4.x;
    Vt[(c4 + 1) * 136 + i] = v4.y;
    Vt[(c4 + 2) * 136 + i] = v4.z;
    Vt[(c4 + 3) * 136 + i] = v4.w;
  }
  __syncthreads();
  const int col = ln & 15, qrow = ln >> 4;
  const float scale = 0.17677669529663687f;  // 32^-0.5
  u16* Psw = &Ps[w][0];
  f32x4 o[2][2] = {{{0.f,0.f,0.f,0.f},{0.f,0.f,0.f,0.f}},{{0.f,0.f,0.f,0.f},{0.f,0.f,0.f,0.f}}};
  for (int tt = 0; tt < 2; ++tt) {
    const int ti = w + tt * 4;
    if (ti >= 7) break;
    const u16* bp = biasFrag + ((long)((h * 7 + ti) * 8) * 64 + ln) * 4;
    ushort4 bfv[8];
#pragma unroll
    for (int tj = 0; tj < 8; ++tj) bfv[tj] = *(const ushort4*)(bp + tj * 256);
    bf16x8 aq = *(const bf16x8*)&Qs[(ti * 16 + col) * 32 + qrow * 8];
    f32x4 s[8];
#pragma unroll
    for (int tj = 0; tj < 8; ++tj) {
      bf16x8 bk = *(const bf16x8*)&Ks[(tj * 16 + col) * 32 + qrow * 8];
      f32x4 z = {0.f, 0.f, 0.f, 0.f};
      s[tj] = __builtin_amdgcn_mfma_f32_16x16x32_bf16(aq, bk, z, 0, 0, 0);
    }
#pragma unroll
    for (int r = 0; r < 4; ++r) {
      float vals[8]; float m = -1e30f;
#pragma unroll
      for (int tj = 0; tj < 8; ++tj) {
        u16 bb = (r == 0) ? bfv[tj].x : (r == 1) ? bfv[tj].y : (r == 2) ? bfv[tj].z : bfv[tj].w;
        float v = fmaf(s[tj][r], scale, b2f(bb));
        vals[tj] = v; m = fmaxf(m, v);
      }
#pragma unroll
      for (int off = 1; off < 16; off <<= 1) m = fmaxf(m, __shfl_xor(m, off));
      float sum = 0.f;
#pragma unroll
      for (int tj = 0; tj < 8; ++tj) { vals[tj] = __expf(vals[tj] - m); sum += vals[tj]; }
#pragma unroll
      for (int off = 1; off < 16; off <<= 1) sum += __shfl_xor(sum, off);
      float inv = 1.f / sum;
      const int rt = qrow * 4 + r;
#pragma unroll
      for (int tj = 0; tj < 8; ++tj)
        Psw[rt * 136 + tj * 16 + col] = f2b(vals[tj] * inv);
    }
#pragma unroll
    for (int ks = 0; ks < 4; ++ks) {
      bf16x8 ap  = *(const bf16x8*)&Psw[col * 136 + ks * 32 + qrow * 8];
      bf16x8 bv0 = *(const bf16x8*)&Vt[col * 136 + ks * 32 + qrow * 8];
      bf16x8 bv1 = *(const bf16x8*)&Vt[(16 + col) * 136 + ks * 32 + qrow * 8];
      o[tt][0] = __builtin_amdgcn_mfma_f32_16x16x32_bf16(ap, bv0, o[tt][0], 0, 0, 0);
      o[tt][1] = __builtin_amdgcn_mfma_f32_16x16x32_bf16(ap, bv1, o[tt][1], 0, 0, 0);
    }
  }
  __syncthreads();   // everyone done reading Qs -> reuse as output staging
  u16* Os = Qs;
#pragma unroll
  for (int tt = 0; tt < 2; ++tt) {
    const int ti = w + tt * 4;
    if (ti >= 7) continue;
#pragma unroll
    for (int r = 0; r < 4; ++r) {
      const int i = ti * 16 + qrow * 4 + r;
      if (i < 98) {
        Os[i * 32 + col]      = f2b(o[tt][0][r]);
        Os[i * 32 + 16 + col] = f2b(o[tt][1][r]);
      }
    }
  }
  __syncthreads();
  // packed store: element (r = b*98+i, k = h*32 + o*8 + j) -> fragment layout.
  // dest u16 index = ((r>>4)*16 + h)*512 + ((r&15) + (o<<4))*8 + j.
  for (int idx = t; idx < 392; idx += 256) {
    int i = idx >> 2, o = idx & 3;
    long r = (long)b * 98 + i;
    u16* dst = attnp + ((r >> 4) * 16 + h) * 512 + ((r & 15) + (o << 4)) * 8;
    const u16* src = &Os[i * 32 + o * 8];
    *(ushort4*)dst = *(const ushort4*)src;
    *(ushort4*)(dst + 4) = *(const ushort4*)(src + 4);
  }
}

extern "C" void kernel_launch(void* const* d_in, const int* in_sizes, int n_in,
                              void* d_out, int out_size, void* d_ws, size_t ws_size,
                              hipStream_t stream) {
  (void)in_sizes; (void)n_in; (void)out_size; (void)ws_size;
  char* p = (char*)d_ws;
  u16* qkvbuf   = (u16*)p;  p += 50176L * 1536 * 2;   // 154,140,672
  u16* attnbuf  = (u16*)p;  u16* xp = attnbuf; p += 50176L * 512 * 2;  // 51,380,224
  u16* wqkvP    = (u16*)p;  p += 1536L * 512 * 2;     // 1,572,864
  u16* wprojP   = (u16*)p;  p += 512L * 512 * 2;      // 524,288
  u16* biasFrag = (u16*)p;  p += 57344L * 4 * 2;      // 458,752
  int* flagp    = (int*)p;

  k_detect<<<1, 64, 0, stream>>>((const u16*)d_in[0], flagp);
  // x -> packed bf16 fragments (50176 fragment units, 1 warp each)
  k_convert_pack<<<12544, 256, 0, stream>>>(d_in[0], xp, flagp);
  k_pack_w<<<384, 256, 0, stream>>>(d_in[1], wqkvP, flagp, 1536);
  k_pack_w<<<128, 256, 0, stream>>>(d_in[3], wprojP, flagp, 512);
  k_biasfrag<<<224, 256, 0, stream>>>((const int*)d_in[6], d_in[5], biasFrag, flagp);
  // qkv = x @ qkv_w + qkv_b   [50176 x 1536], 392x12 tiles of 128^2
  k_gemm_direct<<<dim3(392 * 12), 256, 0, stream>>>(xp, wqkvP, d_in[2], qkvbuf,
                                                    flagp, 1536, 0, 12);
  // attention -> attnbuf (packed fragment order) [50176 x 512]
  k_attn<<<dim3(512, 16), 256, 0, stream>>>(qkvbuf, biasFrag, attnbuf);
  // out = attn @ proj_w + proj_b   [50176 x 512], 392x4 tiles of 128^2
  k_gemm_direct<<<dim3(392 * 4), 256, 0, stream>>>(attnbuf, wprojP, d_in[4], d_out,
                                                   flagp, 512, 1, 4);
}